// Round 3
// baseline (454.420 us; speedup 1.0000x reference)
//
#include <hip/hip_runtime.h>
#include <hip/hip_bf16.h>
#include <math.h>

#define NROWS 65536
#define DIN   512
#define H1    256
#define H2    128
#define K3DIM 384
#define O3    64

typedef short  short8  __attribute__((ext_vector_type(8)));
typedef float  f32x4   __attribute__((ext_vector_type(4)));
typedef unsigned short u16x4 __attribute__((ext_vector_type(4)));

// fp32 -> bf16 bits, round-to-nearest-even
__device__ __forceinline__ unsigned short f2bf(float f) {
    union { float f; unsigned int i; } v; v.f = f;
    unsigned int r = (v.i + 0x7fffu + ((v.i >> 16) & 1u)) >> 16;
    return (unsigned short)r;
}
// bf16 bits -> fp32 (exact)
__device__ __forceinline__ float bf2f(unsigned short u) {
    union { unsigned int i; float f; } v; v.i = ((unsigned int)u) << 16;
    return v.f;
}

// ---------------------------------------------------------------- K0: all W -> W^T bf16 in one launch
__global__ void prep_kernel(const float* __restrict__ W1, const float* __restrict__ W2,
                            const float* __restrict__ W3,
                            unsigned short* __restrict__ w1t, unsigned short* __restrict__ w2t,
                            unsigned short* __restrict__ w3t) {
    int idx = blockIdx.x * 256 + threadIdx.x;
    if (idx < DIN * H1) {                       // W1: [512,256] -> w1t[256][512]
        int c = idx >> 9, r = idx & 511;
        w1t[idx] = f2bf(W1[r * H1 + c]);
    } else if (idx < DIN * H1 + H1 * H2) {      // W2: [256,128] -> w2t[128][256]
        int i2 = idx - DIN * H1;
        int c = i2 >> 8, r = i2 & 255;
        w2t[i2] = f2bf(W2[r * H2 + c]);
    } else if (idx < DIN * H1 + H1 * H2 + K3DIM * O3) {  // W3: [384,64] -> w3t[64][384]
        int i3 = idx - DIN * H1 - H1 * H2;
        int c = i3 / K3DIM, r = i3 - c * K3DIM;
        w3t[i3] = f2bf(W3[r * O3 + c]);
    }
}

// ---------------------------------------------------------------- K1: h = x @ W1 + b1 (bf16 out) + fused col stats
#define LDA 40   // 80B row stride: 16B-aligned, 2-way bank aliasing only

__global__ __launch_bounds__(256, 3)
void gemm1_kernel(const float* __restrict__ x1, const float* __restrict__ x2,
                  const unsigned short* __restrict__ w1t, const float* __restrict__ b1,
                  unsigned short* __restrict__ h_out, float* __restrict__ stats) {
    __shared__ __align__(16) unsigned short Al[128 * LDA];
    __shared__ __align__(16) unsigned short Bl[128 * LDA];
    const int t  = threadIdx.x;
    const int n0 = blockIdx.x * 128;
    const int m0 = blockIdx.y * 128;
    const float* xp = (m0 < NROWS) ? x1 : x2;
    const int inp = (m0 < NROWS) ? 0 : 1;
    const int r0 = m0 & (NROWS - 1);

    const int wave = t >> 6, lane = t & 63;
    const int wm = wave >> 1, wn = wave & 1;
    const int m = lane & 15, q = lane >> 4;

    // staging assignments
    const int ar = t >> 1, ah = t & 1;          // A: row, 16-float half
    const float* abase = xp + (size_t)(r0 + ar) * DIN + ah * 16;
    const unsigned short* bbase = w1t + (size_t)(n0 + ar) * DIN + ah * 16;

    f32x4 acc[4][4] = {};
    float4 pa[4];     // prefetched A (16 fp32)
    float4 pb[2];     // prefetched B (16 bf16)

    // prologue: load k0 = 0
#pragma unroll
    for (int i = 0; i < 4; ++i) pa[i] = *reinterpret_cast<const float4*>(abase + i * 4);
    pb[0] = *reinterpret_cast<const float4*>(bbase);
    pb[1] = *reinterpret_cast<const float4*>(bbase + 8);

    for (int k0 = 0; k0 < DIN; k0 += 32) {
        __syncthreads();
        {   // write prefetched A (cvt fp32->bf16) and B to LDS
            unsigned short ob[16] __attribute__((aligned(16)));
#pragma unroll
            for (int i = 0; i < 4; ++i) {
                ob[4 * i + 0] = f2bf(pa[i].x); ob[4 * i + 1] = f2bf(pa[i].y);
                ob[4 * i + 2] = f2bf(pa[i].z); ob[4 * i + 3] = f2bf(pa[i].w);
            }
            *reinterpret_cast<float4*>(&Al[ar * LDA + ah * 16])     = *reinterpret_cast<float4*>(ob);
            *reinterpret_cast<float4*>(&Al[ar * LDA + ah * 16 + 8]) = *reinterpret_cast<float4*>(ob + 8);
            *reinterpret_cast<float4*>(&Bl[ar * LDA + ah * 16])     = pb[0];
            *reinterpret_cast<float4*>(&Bl[ar * LDA + ah * 16 + 8]) = pb[1];
        }
        __syncthreads();
        // issue next step's loads early (latency hidden behind MFMA + barrier)
        if (k0 + 32 < DIN) {
#pragma unroll
            for (int i = 0; i < 4; ++i) pa[i] = *reinterpret_cast<const float4*>(abase + k0 + 32 + i * 4);
            pb[0] = *reinterpret_cast<const float4*>(bbase + k0 + 32);
            pb[1] = *reinterpret_cast<const float4*>(bbase + k0 + 32 + 8);
        }
        short8 af[4], bfr[4];
#pragma unroll
        for (int mi = 0; mi < 4; ++mi)
            af[mi] = *reinterpret_cast<const short8*>(&Al[(wm * 64 + mi * 16 + m) * LDA + q * 8]);
#pragma unroll
        for (int ni = 0; ni < 4; ++ni)
            bfr[ni] = *reinterpret_cast<const short8*>(&Bl[(wn * 64 + ni * 16 + m) * LDA + q * 8]);
#pragma unroll
        for (int mi = 0; mi < 4; ++mi)
#pragma unroll
            for (int ni = 0; ni < 4; ++ni)
                acc[mi][ni] = __builtin_amdgcn_mfma_f32_16x16x32_bf16(af[mi], bfr[ni], acc[mi][ni], 0, 0, 0);
    }

    // epilogue: bias + store + fused column stats (sum, sumsq over this block's 128 rows)
    float s[4] = {0.f, 0.f, 0.f, 0.f}, ss[4] = {0.f, 0.f, 0.f, 0.f};
#pragma unroll
    for (int ni = 0; ni < 4; ++ni) {
        int col = n0 + wn * 64 + ni * 16 + m;
        float bias = b1[col];
#pragma unroll
        for (int mi = 0; mi < 4; ++mi) {
#pragma unroll
            for (int r = 0; r < 4; ++r) {
                int row = m0 + wm * 64 + mi * 16 + q * 4 + r;
                float v = acc[mi][ni][r] + bias;
                h_out[(size_t)row * H1 + col] = f2bf(v);
                s[ni] += v; ss[ni] += v * v;
            }
        }
    }
#pragma unroll
    for (int ni = 0; ni < 4; ++ni) {
        s[ni]  += __shfl_xor(s[ni], 16);  s[ni]  += __shfl_xor(s[ni], 32);
        ss[ni] += __shfl_xor(ss[ni], 16); ss[ni] += __shfl_xor(ss[ni], 32);
    }
    if (q == 0) {
#pragma unroll
        for (int ni = 0; ni < 4; ++ni) {
            int col = n0 + wn * 64 + ni * 16 + m;
            atomicAdd(&stats[inp * 2 * H1 + col], s[ni]);
            atomicAdd(&stats[inp * 2 * H1 + H1 + col], ss[ni]);
        }
    }
}

// ---------------------------------------------------------------- K2: BN -> per-column affine
__global__ void bnparams_kernel(const float* __restrict__ stats, const float* __restrict__ gamma,
                                const float* __restrict__ beta_bn, float* __restrict__ ab) {
    int t = threadIdx.x;                // 512
    int inp = t >> 8, c = t & 255;
    float mean = stats[(inp * 2 + 0) * H1 + c] * (1.0f / NROWS);
    float ex2  = stats[(inp * 2 + 1) * H1 + c] * (1.0f / NROWS);
    float var  = ex2 - mean * mean;
    float a = gamma[c] * rsqrtf(var + 1e-5f);
    ab[(inp * 2 + 0) * H1 + c] = a;
    ab[(inp * 2 + 1) * H1 + c] = beta_bn[c] - a * mean;
}

// ---------------------------------------------------------------- K3: z = relu(relu(BN(h)) @ W2 + b2)
__global__ __launch_bounds__(256, 3)
void gemm2_kernel(const unsigned short* __restrict__ h, const unsigned short* __restrict__ w2t,
                  const float* __restrict__ b2, const float* __restrict__ ab,
                  unsigned short* __restrict__ z) {
    __shared__ __align__(16) unsigned short Al[128 * LDA];
    __shared__ __align__(16) unsigned short Bl[128 * LDA];
    __shared__ float sc[H1], sh[H1];
    const int t  = threadIdx.x;
    const int m0 = blockIdx.x * 128;
    const int inp = m0 >> 16;
    sc[t & 255] = ab[inp * 2 * H1 + (t & 255)];
    sh[t & 255] = ab[inp * 2 * H1 + H1 + (t & 255)];

    const int wave = t >> 6, lane = t & 63;
    const int wm = wave >> 1, wn = wave & 1;
    const int m = lane & 15, q = lane >> 4;

    const int ar = t >> 1, ah = t & 1;
    const unsigned short* abase = h + (size_t)(m0 + ar) * H1 + ah * 16;
    const unsigned short* bbase = w2t + (size_t)ar * H1 + ah * 16;

    f32x4 acc[4][4] = {};
    float4 pa[2], pb[2];
    pa[0] = *reinterpret_cast<const float4*>(abase);
    pa[1] = *reinterpret_cast<const float4*>(abase + 8);
    pb[0] = *reinterpret_cast<const float4*>(bbase);
    pb[1] = *reinterpret_cast<const float4*>(bbase + 8);

    for (int k0 = 0; k0 < H1; k0 += 32) {
        __syncthreads();
        {   // write prefetched A with BN affine + relu, B raw
            unsigned short vs[16] __attribute__((aligned(16)));
            unsigned short ob[16] __attribute__((aligned(16)));
            *reinterpret_cast<float4*>(vs)     = pa[0];
            *reinterpret_cast<float4*>(vs + 8) = pa[1];
#pragma unroll
            for (int j = 0; j < 16; ++j) {
                int k = k0 + ah * 16 + j;
                float v = sc[k] * bf2f(vs[j]) + sh[k];
                ob[j] = f2bf(fmaxf(v, 0.f));
            }
            *reinterpret_cast<float4*>(&Al[ar * LDA + ah * 16])     = *reinterpret_cast<float4*>(ob);
            *reinterpret_cast<float4*>(&Al[ar * LDA + ah * 16 + 8]) = *reinterpret_cast<float4*>(ob + 8);
            *reinterpret_cast<float4*>(&Bl[ar * LDA + ah * 16])     = pb[0];
            *reinterpret_cast<float4*>(&Bl[ar * LDA + ah * 16 + 8]) = pb[1];
        }
        __syncthreads();
        if (k0 + 32 < H1) {
            pa[0] = *reinterpret_cast<const float4*>(abase + k0 + 32);
            pa[1] = *reinterpret_cast<const float4*>(abase + k0 + 32 + 8);
            pb[0] = *reinterpret_cast<const float4*>(bbase + k0 + 32);
            pb[1] = *reinterpret_cast<const float4*>(bbase + k0 + 32 + 8);
        }
        short8 af[4], bfr[4];
#pragma unroll
        for (int mi = 0; mi < 4; ++mi)
            af[mi] = *reinterpret_cast<const short8*>(&Al[(wm * 64 + mi * 16 + m) * LDA + q * 8]);
#pragma unroll
        for (int ni = 0; ni < 4; ++ni)
            bfr[ni] = *reinterpret_cast<const short8*>(&Bl[(wn * 64 + ni * 16 + m) * LDA + q * 8]);
#pragma unroll
        for (int mi = 0; mi < 4; ++mi)
#pragma unroll
            for (int ni = 0; ni < 4; ++ni)
                acc[mi][ni] = __builtin_amdgcn_mfma_f32_16x16x32_bf16(af[mi], bfr[ni], acc[mi][ni], 0, 0, 0);
    }
#pragma unroll
    for (int mi = 0; mi < 4; ++mi)
#pragma unroll
        for (int ni = 0; ni < 4; ++ni) {
            int col = wn * 64 + ni * 16 + m;
            float bias = b2[col];
#pragma unroll
            for (int r = 0; r < 4; ++r) {
                int row = m0 + wm * 64 + mi * 16 + q * 4 + r;
                z[(size_t)row * H2 + col] = f2bf(fmaxf(acc[mi][ni][r] + bias, 0.f));
            }
        }
}

// ---------------------------------------------------------------- K4: head (cosine + MLP + blend)
#define LDW3 392

__global__ __launch_bounds__(512)
void head_kernel(const unsigned short* __restrict__ z, const unsigned short* __restrict__ w3t,
                 const float* __restrict__ b3, const float* __restrict__ w4,
                 const float* __restrict__ b4, const float* __restrict__ alpha,
                 const float* __restrict__ beta, float* __restrict__ out) {
    __shared__ __align__(16) unsigned short W3l[64 * LDW3];
    __shared__ float b3s[64], w4s[64];
    __shared__ float smath[128], slearn[128];

    const int t  = threadIdx.x;        // 512
    const int r0 = blockIdx.x * 128;

    // stage W3^T: 64 x 384 bf16 (1536 chunks of 16 elems)
#pragma unroll
    for (int i = 0; i < 3; ++i) {
        int c = t + i * 512;
        int n = c / 24, kc = c - n * 24;
        const float4* src = reinterpret_cast<const float4*>(w3t + n * K3DIM + kc * 16);
        float4 v0 = src[0], v1 = src[1];
        *reinterpret_cast<float4*>(&W3l[n * LDW3 + kc * 16])     = v0;
        *reinterpret_cast<float4*>(&W3l[n * LDW3 + kc * 16 + 8]) = v1;
    }
    if (t < 64) { b3s[t] = b3[t]; w4s[t] = w4[t]; }
    __syncthreads();

    const int wave = t >> 6, lane = t & 63;
    const int m = lane & 15, q = lane >> 4;
    const int wr = wave * 16;
    const int row = r0 + wr + m;

    // load this lane's z chunks straight to registers (each elem read by exactly one lane)
    short8 z1c[4], z2c[4];
#pragma unroll
    for (int c = 0; c < 4; ++c) {
        z1c[c] = *reinterpret_cast<const short8*>(z + (size_t)row * H2 + c * 32 + q * 8);
        z2c[c] = *reinterpret_cast<const short8*>(z + (size_t)(NROWS + row) * H2 + c * 32 + q * 8);
    }

    // combined = [z1*z2 | |z1-z2| | z1+z2] @ W3, with cosine accumulated during seg0
    float d = 0.f, s1 = 0.f, s2 = 0.f;
    f32x4 acc[4] = {};
#pragma unroll
    for (int kb = 0; kb < 12; ++kb) {
        int seg = kb >> 2, c = kb & 3;
        short8 af;
#pragma unroll
        for (int j = 0; j < 8; ++j) {
            float v1 = bf2f((unsigned short)z1c[c][j]);
            float v2 = bf2f((unsigned short)z2c[c][j]);
            float v;
            if (seg == 0) { v = v1 * v2; d += v; s1 += v1 * v1; s2 += v2 * v2; }
            else if (seg == 1) v = fabsf(v1 - v2);
            else v = v1 + v2;
            af[j] = (short)f2bf(v);
        }
#pragma unroll
        for (int ni = 0; ni < 4; ++ni) {
            short8 bfr = *reinterpret_cast<const short8*>(&W3l[(ni * 16 + m) * LDW3 + kb * 32 + q * 8]);
            acc[ni] = __builtin_amdgcn_mfma_f32_16x16x32_bf16(af, bfr, acc[ni], 0, 0, 0);
        }
    }
    // cosine: reduce over q (lane bits 4..5)
    d  += __shfl_xor(d, 16);  d  += __shfl_xor(d, 32);
    s1 += __shfl_xor(s1, 16); s1 += __shfl_xor(s1, 32);
    s2 += __shfl_xor(s2, 16); s2 += __shfl_xor(s2, 32);
    if (q == 0) {
        float inv1 = 1.f / fmaxf(sqrtf(s1), 1e-15f);
        float inv2 = 1.f / fmaxf(sqrtf(s2), 1e-15f);
        smath[wr + m] = fminf(fmaxf(d * inv1 * inv2, 0.f), 1.f);
    }

    // MLP epilogue: relu(acc+b3) . w4, reduce over m (lane bits 0..3)
    float partial[4] = {0.f, 0.f, 0.f, 0.f};
#pragma unroll
    for (int ni = 0; ni < 4; ++ni) {
        int col = ni * 16 + m;
        float bias = b3s[col], w4v = w4s[col];
#pragma unroll
        for (int rg = 0; rg < 4; ++rg) {
            float v = fmaxf(acc[ni][rg] + bias, 0.f);
            partial[rg] += v * w4v;
        }
    }
#pragma unroll
    for (int rg = 0; rg < 4; ++rg) {
        float p = partial[rg];
        p += __shfl_xor(p, 1); p += __shfl_xor(p, 2);
        p += __shfl_xor(p, 4); p += __shfl_xor(p, 8);
        if (m == 0) slearn[wr + q * 4 + rg] = p + b4[0];
    }
    __syncthreads();
    if (t < 128) {
        float sl = slearn[t];
        float sig = 1.f / (1.f + expf(-sl));
        float f = alpha[0] * smath[t] + beta[0] * sig;
        out[r0 + t] = fminf(fmaxf(f, 0.f), 1.f);
    }
}

// ---------------------------------------------------------------- launch
extern "C" void kernel_launch(void* const* d_in, const int* in_sizes, int n_in,
                              void* d_out, int out_size, void* d_ws, size_t ws_size,
                              hipStream_t stream) {
    (void)in_sizes; (void)n_in; (void)out_size; (void)ws_size;
    const float* x1      = (const float*)d_in[0];
    const float* x2      = (const float*)d_in[1];
    const float* W1      = (const float*)d_in[2];
    const float* b1      = (const float*)d_in[3];
    const float* gamma   = (const float*)d_in[4];
    const float* beta_bn = (const float*)d_in[5];
    const float* W2      = (const float*)d_in[6];
    const float* b2      = (const float*)d_in[7];
    const float* W3      = (const float*)d_in[8];
    const float* b3      = (const float*)d_in[9];
    const float* W4      = (const float*)d_in[10];
    const float* b4      = (const float*)d_in[11];
    const float* alpha   = (const float*)d_in[12];
    const float* beta    = (const float*)d_in[13];
    float* out = (float*)d_out;

    char* ws = (char*)d_ws;
    unsigned short* h   = (unsigned short*)(ws);                  // 67108864 B
    unsigned short* w1t = (unsigned short*)(ws + 67108864);       // 262144 B
    unsigned short* w2t = (unsigned short*)(ws + 67371008);       // 65536 B
    unsigned short* w3t = (unsigned short*)(ws + 67436544);       // 49152 B
    float*          stats = (float*)(ws + 67485696);              // 4096 B
    float*          ab    = (float*)(ws + 67489792);              // 4096 B
    unsigned short* z   = (unsigned short*)(ws + 67493888);       // 33554432 B

    (void)hipMemsetAsync(stats, 0, 4096, stream);
    prep_kernel<<<(DIN * H1 + H1 * H2 + K3DIM * O3 + 255) / 256, 256, 0, stream>>>(W1, W2, W3, w1t, w2t, w3t);
    gemm1_kernel<<<dim3(2, 1024), 256, 0, stream>>>(x1, x2, w1t, b1, h, stats);
    bnparams_kernel<<<1, 512, 0, stream>>>(stats, gamma, beta_bn, ab);
    gemm2_kernel<<<1024, 256, 0, stream>>>(h, w2t, b2, ab, z);
    head_kernel<<<512, 512, 0, stream>>>(z, w3t, b3, W4, b4, alpha, beta, out);
}

// Round 4
// 453.701 us; speedup vs baseline: 1.0016x; 1.0016x over previous
//
#include <hip/hip_runtime.h>
#include <hip/hip_bf16.h>
#include <math.h>

#define NROWS 65536
#define DIN   512
#define H1    256
#define H2    128
#define K3DIM 384
#define O3    64

typedef short  short8  __attribute__((ext_vector_type(8)));
typedef float  f32x4   __attribute__((ext_vector_type(4)));
typedef unsigned short u16x4 __attribute__((ext_vector_type(4)));

// fp32 -> bf16 bits, round-to-nearest-even
__device__ __forceinline__ unsigned short f2bf(float f) {
    union { float f; unsigned int i; } v; v.f = f;
    unsigned int r = (v.i + 0x7fffu + ((v.i >> 16) & 1u)) >> 16;
    return (unsigned short)r;
}
// bf16 bits -> fp32 (exact)
__device__ __forceinline__ float bf2f(unsigned short u) {
    union { unsigned int i; float f; } v; v.i = ((unsigned int)u) << 16;
    return v.f;
}

// ---------------------------------------------------------------- K0: all W -> W^T bf16 in one launch
__global__ void prep_kernel(const float* __restrict__ W1, const float* __restrict__ W2,
                            const float* __restrict__ W3,
                            unsigned short* __restrict__ w1t, unsigned short* __restrict__ w2t,
                            unsigned short* __restrict__ w3t) {
    int idx = blockIdx.x * 256 + threadIdx.x;
    if (idx < DIN * H1) {                       // W1: [512,256] -> w1t[256][512]
        int c = idx >> 9, r = idx & 511;
        w1t[idx] = f2bf(W1[r * H1 + c]);
    } else if (idx < DIN * H1 + H1 * H2) {      // W2: [256,128] -> w2t[128][256]
        int i2 = idx - DIN * H1;
        int c = i2 >> 8, r = i2 & 255;
        w2t[i2] = f2bf(W2[r * H2 + c]);
    } else if (idx < DIN * H1 + H1 * H2 + K3DIM * O3) {  // W3: [384,64] -> w3t[64][384]
        int i3 = idx - DIN * H1 - H1 * H2;
        int c = i3 / K3DIM, r = i3 - c * K3DIM;
        w3t[i3] = f2bf(W3[r * O3 + c]);
    }
}

// ---------------------------------------------------------------- K1: h = x @ W1 + b1 (bf16 out) + fused col stats
#define LDA 40   // 80B row stride: 16B-aligned

__global__ __launch_bounds__(256, 4)
void gemm1_kernel(const float* __restrict__ x1, const float* __restrict__ x2,
                  const unsigned short* __restrict__ w1t, const float* __restrict__ b1,
                  unsigned short* __restrict__ h_out, float* __restrict__ stats) {
    __shared__ __align__(16) unsigned short Al[128 * LDA];
    __shared__ __align__(16) unsigned short Bl[128 * LDA];
    const int t  = threadIdx.x;
    const int n0 = blockIdx.x * 128;
    const int m0 = blockIdx.y * 128;
    const float* xp = (m0 < NROWS) ? x1 : x2;
    const int inp = (m0 < NROWS) ? 0 : 1;
    const int r0 = m0 & (NROWS - 1);

    const int wave = t >> 6, lane = t & 63;
    const int wm = wave >> 1, wn = wave & 1;
    const int m = lane & 15, q = lane >> 4;

    // staging assignments
    const int ar = t >> 1, ah = t & 1;          // A: row, 16-float half
    const float* abase = xp + (size_t)(r0 + ar) * DIN + ah * 16;
    const unsigned short* bbase = w1t + (size_t)(n0 + ar) * DIN + ah * 16;

    f32x4 acc[4][4] = {};
    float4 pa[4];     // prefetched A (16 fp32)
    float4 pb[2];     // prefetched B (16 bf16)

    // prologue: load k0 = 0
#pragma unroll
    for (int i = 0; i < 4; ++i) pa[i] = *reinterpret_cast<const float4*>(abase + i * 4);
    pb[0] = *reinterpret_cast<const float4*>(bbase);
    pb[1] = *reinterpret_cast<const float4*>(bbase + 8);

    for (int k0 = 0; k0 < DIN; k0 += 32) {
        __syncthreads();
        {   // write prefetched A (cvt fp32->bf16) and B to LDS
            unsigned short ob[16] __attribute__((aligned(16)));
#pragma unroll
            for (int i = 0; i < 4; ++i) {
                ob[4 * i + 0] = f2bf(pa[i].x); ob[4 * i + 1] = f2bf(pa[i].y);
                ob[4 * i + 2] = f2bf(pa[i].z); ob[4 * i + 3] = f2bf(pa[i].w);
            }
            *reinterpret_cast<float4*>(&Al[ar * LDA + ah * 16])     = *reinterpret_cast<float4*>(ob);
            *reinterpret_cast<float4*>(&Al[ar * LDA + ah * 16 + 8]) = *reinterpret_cast<float4*>(ob + 8);
            *reinterpret_cast<float4*>(&Bl[ar * LDA + ah * 16])     = pb[0];
            *reinterpret_cast<float4*>(&Bl[ar * LDA + ah * 16 + 8]) = pb[1];
        }
        __syncthreads();
        // issue next step's loads early (latency hidden behind MFMA + barrier)
        if (k0 + 32 < DIN) {
#pragma unroll
            for (int i = 0; i < 4; ++i) pa[i] = *reinterpret_cast<const float4*>(abase + k0 + 32 + i * 4);
            pb[0] = *reinterpret_cast<const float4*>(bbase + k0 + 32);
            pb[1] = *reinterpret_cast<const float4*>(bbase + k0 + 32 + 8);
        }
        short8 af[4], bfr[4];
#pragma unroll
        for (int mi = 0; mi < 4; ++mi)
            af[mi] = *reinterpret_cast<const short8*>(&Al[(wm * 64 + mi * 16 + m) * LDA + q * 8]);
#pragma unroll
        for (int ni = 0; ni < 4; ++ni)
            bfr[ni] = *reinterpret_cast<const short8*>(&Bl[(wn * 64 + ni * 16 + m) * LDA + q * 8]);
#pragma unroll
        for (int mi = 0; mi < 4; ++mi)
#pragma unroll
            for (int ni = 0; ni < 4; ++ni)
                acc[mi][ni] = __builtin_amdgcn_mfma_f32_16x16x32_bf16(af[mi], bfr[ni], acc[mi][ni], 0, 0, 0);
    }

    // epilogue: bias + store + fused column stats.
    // CRITICAL: ni is the innermost loop so the two stores that fill one
    // 64B cacheline (ni pairs at the same row) are adjacent and merge in the
    // write-combine path. (ni-outer order cost 4x HBM write traffic — R3.)
    float s[4] = {0.f, 0.f, 0.f, 0.f}, ss[4] = {0.f, 0.f, 0.f, 0.f};
    float bias[4];
#pragma unroll
    for (int ni = 0; ni < 4; ++ni) bias[ni] = b1[n0 + wn * 64 + ni * 16 + m];
#pragma unroll
    for (int mi = 0; mi < 4; ++mi) {
#pragma unroll
        for (int r = 0; r < 4; ++r) {
            int row = m0 + wm * 64 + mi * 16 + q * 4 + r;
#pragma unroll
            for (int ni = 0; ni < 4; ++ni) {
                int col = n0 + wn * 64 + ni * 16 + m;
                float v = acc[mi][ni][r] + bias[ni];
                h_out[(size_t)row * H1 + col] = f2bf(v);
                s[ni] += v; ss[ni] += v * v;
            }
        }
    }
#pragma unroll
    for (int ni = 0; ni < 4; ++ni) {
        s[ni]  += __shfl_xor(s[ni], 16);  s[ni]  += __shfl_xor(s[ni], 32);
        ss[ni] += __shfl_xor(ss[ni], 16); ss[ni] += __shfl_xor(ss[ni], 32);
    }
    if (q == 0) {
#pragma unroll
        for (int ni = 0; ni < 4; ++ni) {
            int col = n0 + wn * 64 + ni * 16 + m;
            atomicAdd(&stats[inp * 2 * H1 + col], s[ni]);
            atomicAdd(&stats[inp * 2 * H1 + H1 + col], ss[ni]);
        }
    }
}

// ---------------------------------------------------------------- K2: BN -> per-column affine
__global__ void bnparams_kernel(const float* __restrict__ stats, const float* __restrict__ gamma,
                                const float* __restrict__ beta_bn, float* __restrict__ ab) {
    int t = threadIdx.x;                // 512
    int inp = t >> 8, c = t & 255;
    float mean = stats[(inp * 2 + 0) * H1 + c] * (1.0f / NROWS);
    float ex2  = stats[(inp * 2 + 1) * H1 + c] * (1.0f / NROWS);
    float var  = ex2 - mean * mean;
    float a = gamma[c] * rsqrtf(var + 1e-5f);
    ab[(inp * 2 + 0) * H1 + c] = a;
    ab[(inp * 2 + 1) * H1 + c] = beta_bn[c] - a * mean;
}

// ---------------------------------------------------------------- K3: z = relu(relu(BN(h)) @ W2 + b2)
__global__ __launch_bounds__(256, 4)
void gemm2_kernel(const unsigned short* __restrict__ h, const unsigned short* __restrict__ w2t,
                  const float* __restrict__ b2, const float* __restrict__ ab,
                  unsigned short* __restrict__ z) {
    __shared__ __align__(16) unsigned short Al[128 * LDA];
    __shared__ __align__(16) unsigned short Bl[128 * LDA];
    __shared__ float sc[H1], sh[H1];
    const int t  = threadIdx.x;
    const int m0 = blockIdx.x * 128;
    const int inp = m0 >> 16;
    sc[t & 255] = ab[inp * 2 * H1 + (t & 255)];
    sh[t & 255] = ab[inp * 2 * H1 + H1 + (t & 255)];

    const int wave = t >> 6, lane = t & 63;
    const int wm = wave >> 1, wn = wave & 1;
    const int m = lane & 15, q = lane >> 4;

    const int ar = t >> 1, ah = t & 1;
    const unsigned short* abase = h + (size_t)(m0 + ar) * H1 + ah * 16;
    const unsigned short* bbase = w2t + (size_t)ar * H1 + ah * 16;

    f32x4 acc[4][4] = {};
    float4 pa[2], pb[2];
    pa[0] = *reinterpret_cast<const float4*>(abase);
    pa[1] = *reinterpret_cast<const float4*>(abase + 8);
    pb[0] = *reinterpret_cast<const float4*>(bbase);
    pb[1] = *reinterpret_cast<const float4*>(bbase + 8);

    for (int k0 = 0; k0 < H1; k0 += 32) {
        __syncthreads();
        {   // write prefetched A with BN affine + relu, B raw
            unsigned short vs[16] __attribute__((aligned(16)));
            unsigned short ob[16] __attribute__((aligned(16)));
            *reinterpret_cast<float4*>(vs)     = pa[0];
            *reinterpret_cast<float4*>(vs + 8) = pa[1];
#pragma unroll
            for (int j = 0; j < 16; ++j) {
                int k = k0 + ah * 16 + j;
                float v = sc[k] * bf2f(vs[j]) + sh[k];
                ob[j] = f2bf(fmaxf(v, 0.f));
            }
            *reinterpret_cast<float4*>(&Al[ar * LDA + ah * 16])     = *reinterpret_cast<float4*>(ob);
            *reinterpret_cast<float4*>(&Al[ar * LDA + ah * 16 + 8]) = *reinterpret_cast<float4*>(ob + 8);
            *reinterpret_cast<float4*>(&Bl[ar * LDA + ah * 16])     = pb[0];
            *reinterpret_cast<float4*>(&Bl[ar * LDA + ah * 16 + 8]) = pb[1];
        }
        __syncthreads();
        if (k0 + 32 < H1) {
            pa[0] = *reinterpret_cast<const float4*>(abase + k0 + 32);
            pa[1] = *reinterpret_cast<const float4*>(abase + k0 + 32 + 8);
            pb[0] = *reinterpret_cast<const float4*>(bbase + k0 + 32);
            pb[1] = *reinterpret_cast<const float4*>(bbase + k0 + 32 + 8);
        }
        short8 af[4], bfr[4];
#pragma unroll
        for (int mi = 0; mi < 4; ++mi)
            af[mi] = *reinterpret_cast<const short8*>(&Al[(wm * 64 + mi * 16 + m) * LDA + q * 8]);
#pragma unroll
        for (int ni = 0; ni < 4; ++ni)
            bfr[ni] = *reinterpret_cast<const short8*>(&Bl[(wn * 64 + ni * 16 + m) * LDA + q * 8]);
#pragma unroll
        for (int mi = 0; mi < 4; ++mi)
#pragma unroll
            for (int ni = 0; ni < 4; ++ni)
                acc[mi][ni] = __builtin_amdgcn_mfma_f32_16x16x32_bf16(af[mi], bfr[ni], acc[mi][ni], 0, 0, 0);
    }
    // epilogue: ni innermost for same-line store adjacency (see gemm1 note)
    float bias[4];
#pragma unroll
    for (int ni = 0; ni < 4; ++ni) bias[ni] = b2[wn * 64 + ni * 16 + m];
#pragma unroll
    for (int mi = 0; mi < 4; ++mi) {
#pragma unroll
        for (int r = 0; r < 4; ++r) {
            int row = m0 + wm * 64 + mi * 16 + q * 4 + r;
#pragma unroll
            for (int ni = 0; ni < 4; ++ni) {
                int col = wn * 64 + ni * 16 + m;
                z[(size_t)row * H2 + col] = f2bf(fmaxf(acc[mi][ni][r] + bias[ni], 0.f));
            }
        }
    }
}

// ---------------------------------------------------------------- K4: head (cosine + MLP + blend)
#define LDW3 392

__global__ __launch_bounds__(512)
void head_kernel(const unsigned short* __restrict__ z, const unsigned short* __restrict__ w3t,
                 const float* __restrict__ b3, const float* __restrict__ w4,
                 const float* __restrict__ b4, const float* __restrict__ alpha,
                 const float* __restrict__ beta, float* __restrict__ out) {
    __shared__ __align__(16) unsigned short W3l[64 * LDW3];
    __shared__ float b3s[64], w4s[64];
    __shared__ float smath[128], slearn[128];

    const int t  = threadIdx.x;        // 512
    const int r0 = blockIdx.x * 128;

    // stage W3^T: 64 x 384 bf16 (1536 chunks of 16 elems)
#pragma unroll
    for (int i = 0; i < 3; ++i) {
        int c = t + i * 512;
        int n = c / 24, kc = c - n * 24;
        const float4* src = reinterpret_cast<const float4*>(w3t + n * K3DIM + kc * 16);
        float4 v0 = src[0], v1 = src[1];
        *reinterpret_cast<float4*>(&W3l[n * LDW3 + kc * 16])     = v0;
        *reinterpret_cast<float4*>(&W3l[n * LDW3 + kc * 16 + 8]) = v1;
    }
    if (t < 64) { b3s[t] = b3[t]; w4s[t] = w4[t]; }
    __syncthreads();

    const int wave = t >> 6, lane = t & 63;
    const int m = lane & 15, q = lane >> 4;
    const int wr = wave * 16;
    const int row = r0 + wr + m;

    // load this lane's z chunks straight to registers (each elem read by exactly one lane)
    short8 z1c[4], z2c[4];
#pragma unroll
    for (int c = 0; c < 4; ++c) {
        z1c[c] = *reinterpret_cast<const short8*>(z + (size_t)row * H2 + c * 32 + q * 8);
        z2c[c] = *reinterpret_cast<const short8*>(z + (size_t)(NROWS + row) * H2 + c * 32 + q * 8);
    }

    // combined = [z1*z2 | |z1-z2| | z1+z2] @ W3, with cosine accumulated during seg0
    float d = 0.f, s1 = 0.f, s2 = 0.f;
    f32x4 acc[4] = {};
#pragma unroll
    for (int kb = 0; kb < 12; ++kb) {
        int seg = kb >> 2, c = kb & 3;
        short8 af;
#pragma unroll
        for (int j = 0; j < 8; ++j) {
            float v1 = bf2f((unsigned short)z1c[c][j]);
            float v2 = bf2f((unsigned short)z2c[c][j]);
            float v;
            if (seg == 0) { v = v1 * v2; d += v; s1 += v1 * v1; s2 += v2 * v2; }
            else if (seg == 1) v = fabsf(v1 - v2);
            else v = v1 + v2;
            af[j] = (short)f2bf(v);
        }
#pragma unroll
        for (int ni = 0; ni < 4; ++ni) {
            short8 bfr = *reinterpret_cast<const short8*>(&W3l[(ni * 16 + m) * LDW3 + kb * 32 + q * 8]);
            acc[ni] = __builtin_amdgcn_mfma_f32_16x16x32_bf16(af, bfr, acc[ni], 0, 0, 0);
        }
    }
    // cosine: reduce over q (lane bits 4..5)
    d  += __shfl_xor(d, 16);  d  += __shfl_xor(d, 32);
    s1 += __shfl_xor(s1, 16); s1 += __shfl_xor(s1, 32);
    s2 += __shfl_xor(s2, 16); s2 += __shfl_xor(s2, 32);
    if (q == 0) {
        float inv1 = 1.f / fmaxf(sqrtf(s1), 1e-15f);
        float inv2 = 1.f / fmaxf(sqrtf(s2), 1e-15f);
        smath[wr + m] = fminf(fmaxf(d * inv1 * inv2, 0.f), 1.f);
    }

    // MLP epilogue: relu(acc+b3) . w4, reduce over m (lane bits 0..3)
    float partial[4] = {0.f, 0.f, 0.f, 0.f};
#pragma unroll
    for (int ni = 0; ni < 4; ++ni) {
        int col = ni * 16 + m;
        float bias = b3s[col], w4v = w4s[col];
#pragma unroll
        for (int rg = 0; rg < 4; ++rg) {
            float v = fmaxf(acc[ni][rg] + bias, 0.f);
            partial[rg] += v * w4v;
        }
    }
#pragma unroll
    for (int rg = 0; rg < 4; ++rg) {
        float p = partial[rg];
        p += __shfl_xor(p, 1); p += __shfl_xor(p, 2);
        p += __shfl_xor(p, 4); p += __shfl_xor(p, 8);
        if (m == 0) slearn[wr + q * 4 + rg] = p + b4[0];
    }
    __syncthreads();
    if (t < 128) {
        float sl = slearn[t];
        float sig = 1.f / (1.f + expf(-sl));
        float f = alpha[0] * smath[t] + beta[0] * sig;
        out[r0 + t] = fminf(fmaxf(f, 0.f), 1.f);
    }
}

// ---------------------------------------------------------------- launch
extern "C" void kernel_launch(void* const* d_in, const int* in_sizes, int n_in,
                              void* d_out, int out_size, void* d_ws, size_t ws_size,
                              hipStream_t stream) {
    (void)in_sizes; (void)n_in; (void)out_size; (void)ws_size;
    const float* x1      = (const float*)d_in[0];
    const float* x2      = (const float*)d_in[1];
    const float* W1      = (const float*)d_in[2];
    const float* b1      = (const float*)d_in[3];
    const float* gamma   = (const float*)d_in[4];
    const float* beta_bn = (const float*)d_in[5];
    const float* W2      = (const float*)d_in[6];
    const float* b2      = (const float*)d_in[7];
    const float* W3      = (const float*)d_in[8];
    const float* b3      = (const float*)d_in[9];
    const float* W4      = (const float*)d_in[10];
    const float* b4      = (const float*)d_in[11];
    const float* alpha   = (const float*)d_in[12];
    const float* beta    = (const float*)d_in[13];
    float* out = (float*)d_out;

    char* ws = (char*)d_ws;
    unsigned short* h   = (unsigned short*)(ws);                  // 67108864 B
    unsigned short* w1t = (unsigned short*)(ws + 67108864);       // 262144 B
    unsigned short* w2t = (unsigned short*)(ws + 67371008);       // 65536 B
    unsigned short* w3t = (unsigned short*)(ws + 67436544);       // 49152 B
    float*          stats = (float*)(ws + 67485696);              // 4096 B
    float*          ab    = (float*)(ws + 67489792);              // 4096 B
    unsigned short* z   = (unsigned short*)(ws + 67493888);       // 33554432 B

    (void)hipMemsetAsync(stats, 0, 4096, stream);
    prep_kernel<<<(DIN * H1 + H1 * H2 + K3DIM * O3 + 255) / 256, 256, 0, stream>>>(W1, W2, W3, w1t, w2t, w3t);
    gemm1_kernel<<<dim3(2, 1024), 256, 0, stream>>>(x1, x2, w1t, b1, h, stats);
    bnparams_kernel<<<1, 512, 0, stream>>>(stats, gamma, beta_bn, ab);
    gemm2_kernel<<<1024, 256, 0, stream>>>(h, w2t, b2, ab, z);
    head_kernel<<<512, 512, 0, stream>>>(z, w3t, b3, W4, b4, alpha, beta, out);
}

// Round 5
// 426.557 us; speedup vs baseline: 1.0653x; 1.0636x over previous
//
#include <hip/hip_runtime.h>
#include <hip/hip_bf16.h>
#include <math.h>

#define NROWS 65536
#define DIN   512
#define H1    256
#define H2    128
#define K3DIM 384
#define O3    64

typedef short  short8  __attribute__((ext_vector_type(8)));
typedef float  f32x4   __attribute__((ext_vector_type(4)));
typedef unsigned short u16x4 __attribute__((ext_vector_type(4)));

// fp32 -> bf16 bits, round-to-nearest-even
__device__ __forceinline__ unsigned short f2bf(float f) {
    union { float f; unsigned int i; } v; v.f = f;
    unsigned int r = (v.i + 0x7fffu + ((v.i >> 16) & 1u)) >> 16;
    return (unsigned short)r;
}
// bf16 bits -> fp32 (exact)
__device__ __forceinline__ float bf2f(unsigned short u) {
    union { unsigned int i; float f; } v; v.i = ((unsigned int)u) << 16;
    return v.f;
}

// ---------------------------------------------------------------- K0: all W -> W^T bf16 in one launch
__global__ void prep_kernel(const float* __restrict__ W1, const float* __restrict__ W2,
                            const float* __restrict__ W3,
                            unsigned short* __restrict__ w1t, unsigned short* __restrict__ w2t,
                            unsigned short* __restrict__ w3t) {
    int idx = blockIdx.x * 256 + threadIdx.x;
    if (idx < DIN * H1) {                       // W1: [512,256] -> w1t[256][512]
        int c = idx >> 9, r = idx & 511;
        w1t[idx] = f2bf(W1[r * H1 + c]);
    } else if (idx < DIN * H1 + H1 * H2) {      // W2: [256,128] -> w2t[128][256]
        int i2 = idx - DIN * H1;
        int c = i2 >> 8, r = i2 & 255;
        w2t[i2] = f2bf(W2[r * H2 + c]);
    } else if (idx < DIN * H1 + H1 * H2 + K3DIM * O3) {  // W3: [384,64] -> w3t[64][384]
        int i3 = idx - DIN * H1 - H1 * H2;
        int c = i3 / K3DIM, r = i3 - c * K3DIM;
        w3t[i3] = f2bf(W3[r * O3 + c]);
    }
}

// ---------------------------------------------------------------- K1: h = x @ W1 + b1 (bf16 out) + per-block partial stats
#define LDA 40   // 80B row stride: 16B-aligned

// R2-proven structure (129 us, 66 MB writes). NO atomics: stats partials go to
// P[arr][mslot][col] as plain stores (mslot = blockIdx.y*2 + wm), reduced by
// reduce_bn_kernel. R3/R4's fused atomicAdd stats cost +70 us and 3.5x HBM
// writes (device-scope atomics = memory-side RMW).
__global__ __launch_bounds__(256, 2)
void gemm1_kernel(const float* __restrict__ x1, const float* __restrict__ x2,
                  const unsigned short* __restrict__ w1t, const float* __restrict__ b1,
                  unsigned short* __restrict__ h_out, float* __restrict__ P) {
    __shared__ __align__(16) unsigned short Al[128 * LDA];
    __shared__ __align__(16) unsigned short Bl[128 * LDA];
    const int t  = threadIdx.x;
    const int n0 = blockIdx.x * 128;
    const int m0 = blockIdx.y * 128;
    const float* xp = (m0 < NROWS) ? x1 : x2;
    const int r0 = m0 & (NROWS - 1);

    const int wave = t >> 6, lane = t & 63;
    const int wm = wave >> 1, wn = wave & 1;
    const int m = lane & 15, q = lane >> 4;

    f32x4 acc[4][4] = {};

    for (int k0 = 0; k0 < DIN; k0 += 32) {
        __syncthreads();
        // stage A: 128 rows x 32 k, fp32 -> bf16 inline
#pragma unroll
        for (int i = 0; i < 4; ++i) {
            int u = t + i * 256;
            int r = u >> 3, kq = u & 7;
            const float4 v = *reinterpret_cast<const float4*>(xp + (size_t)(r0 + r) * DIN + k0 + kq * 4);
            u16x4 b; b.x = f2bf(v.x); b.y = f2bf(v.y); b.z = f2bf(v.z); b.w = f2bf(v.w);
            *reinterpret_cast<u16x4*>(&Al[r * LDA + kq * 4]) = b;
        }
        // stage B: 128 n-rows x 32 k from W1^T (bf16)
        {
            int n = t >> 1, kh = t & 1;
            const float4* src = reinterpret_cast<const float4*>(w1t + (size_t)(n0 + n) * DIN + k0 + kh * 16);
            float4 v0 = src[0], v1 = src[1];
            *reinterpret_cast<float4*>(&Bl[n * LDA + kh * 16])     = v0;
            *reinterpret_cast<float4*>(&Bl[n * LDA + kh * 16 + 8]) = v1;
        }
        __syncthreads();
        short8 af[4], bfr[4];
#pragma unroll
        for (int mi = 0; mi < 4; ++mi)
            af[mi] = *reinterpret_cast<const short8*>(&Al[(wm * 64 + mi * 16 + m) * LDA + q * 8]);
#pragma unroll
        for (int ni = 0; ni < 4; ++ni)
            bfr[ni] = *reinterpret_cast<const short8*>(&Bl[(wn * 64 + ni * 16 + m) * LDA + q * 8]);
#pragma unroll
        for (int mi = 0; mi < 4; ++mi)
#pragma unroll
            for (int ni = 0; ni < 4; ++ni)
                acc[mi][ni] = __builtin_amdgcn_mfma_f32_16x16x32_bf16(af[mi], bfr[ni], acc[mi][ni], 0, 0, 0);
    }

    // epilogue: R2 loop order (proven 66 MB writes) + stats accumulation
    float s[4] = {0.f, 0.f, 0.f, 0.f}, ss[4] = {0.f, 0.f, 0.f, 0.f};
#pragma unroll
    for (int mi = 0; mi < 4; ++mi)
#pragma unroll
        for (int ni = 0; ni < 4; ++ni) {
            int col = n0 + wn * 64 + ni * 16 + m;
            float bias = b1[col];
#pragma unroll
            for (int r = 0; r < 4; ++r) {
                int row = m0 + wm * 64 + mi * 16 + q * 4 + r;
                float v = acc[mi][ni][r] + bias;
                h_out[(size_t)row * H1 + col] = f2bf(v);
                s[ni] += v; ss[ni] += v * v;
            }
        }
    // q-reduce (rows q*4+r within the wm half), then plain stores — no atomics
#pragma unroll
    for (int ni = 0; ni < 4; ++ni) {
        s[ni]  += __shfl_xor(s[ni], 16);  s[ni]  += __shfl_xor(s[ni], 32);
        ss[ni] += __shfl_xor(ss[ni], 16); ss[ni] += __shfl_xor(ss[ni], 32);
    }
    if (q == 0) {
        const size_t mslot = (size_t)blockIdx.y * 2 + wm;   // 0..2047
#pragma unroll
        for (int ni = 0; ni < 4; ++ni) {
            int col = n0 + wn * 64 + ni * 16 + m;
            P[mslot * 256 + col]                 = s[ni];
            P[(size_t)524288 + mslot * 256 + col] = ss[ni];
        }
    }
}

// ---------------------------------------------------------------- K2: reduce partials -> BN per-column affine
__global__ __launch_bounds__(512)
void reduce_bn_kernel(const float* __restrict__ P, const float* __restrict__ gamma,
                      const float* __restrict__ beta_bn, float* __restrict__ ab) {
    __shared__ float Ssum[256], SSsum[256];
    const int inp = blockIdx.x;        // 2 blocks
    const int t = threadIdx.x;         // 512
    const int arr = t >> 8, col = t & 255;
    const float* base = P + (size_t)arr * 524288 + (size_t)inp * 1024 * 256 + col;
    float a0 = 0.f, a1 = 0.f, a2 = 0.f, a3 = 0.f;
    for (int ms = 0; ms < 1024; ms += 4) {
        a0 += base[(ms + 0) * 256]; a1 += base[(ms + 1) * 256];
        a2 += base[(ms + 2) * 256]; a3 += base[(ms + 3) * 256];
    }
    float tot = (a0 + a1) + (a2 + a3);
    if (arr == 0) Ssum[col] = tot; else SSsum[col] = tot;
    __syncthreads();
    if (t < 256) {
        float mean = Ssum[t] * (1.0f / NROWS);
        float ex2  = SSsum[t] * (1.0f / NROWS);
        float var  = ex2 - mean * mean;
        float a = gamma[t] * rsqrtf(var + 1e-5f);
        ab[inp * 2 * H1 + t]      = a;
        ab[inp * 2 * H1 + H1 + t] = beta_bn[t] - a * mean;
    }
}

// ---------------------------------------------------------------- K3: z = relu(relu(BN(h)) @ W2 + b2)
__global__ __launch_bounds__(256, 4)
void gemm2_kernel(const unsigned short* __restrict__ h, const unsigned short* __restrict__ w2t,
                  const float* __restrict__ b2, const float* __restrict__ ab,
                  unsigned short* __restrict__ z) {
    __shared__ __align__(16) unsigned short Al[128 * LDA];
    __shared__ __align__(16) unsigned short Bl[128 * LDA];
    __shared__ float sc[H1], sh[H1];
    const int t  = threadIdx.x;
    const int m0 = blockIdx.x * 128;
    const int inp = m0 >> 16;
    sc[t & 255] = ab[inp * 2 * H1 + (t & 255)];
    sh[t & 255] = ab[inp * 2 * H1 + H1 + (t & 255)];

    const int wave = t >> 6, lane = t & 63;
    const int wm = wave >> 1, wn = wave & 1;
    const int m = lane & 15, q = lane >> 4;

    const int ar = t >> 1, ah = t & 1;
    const unsigned short* abase = h + (size_t)(m0 + ar) * H1 + ah * 16;
    const unsigned short* bbase = w2t + (size_t)ar * H1 + ah * 16;

    f32x4 acc[4][4] = {};
    float4 pa[2], pb[2];
    pa[0] = *reinterpret_cast<const float4*>(abase);
    pa[1] = *reinterpret_cast<const float4*>(abase + 8);
    pb[0] = *reinterpret_cast<const float4*>(bbase);
    pb[1] = *reinterpret_cast<const float4*>(bbase + 8);

    for (int k0 = 0; k0 < H1; k0 += 32) {
        __syncthreads();
        {   // write prefetched A with BN affine + relu, B raw
            unsigned short vs[16] __attribute__((aligned(16)));
            unsigned short ob[16] __attribute__((aligned(16)));
            *reinterpret_cast<float4*>(vs)     = pa[0];
            *reinterpret_cast<float4*>(vs + 8) = pa[1];
#pragma unroll
            for (int j = 0; j < 16; ++j) {
                int k = k0 + ah * 16 + j;
                float v = sc[k] * bf2f(vs[j]) + sh[k];
                ob[j] = f2bf(fmaxf(v, 0.f));
            }
            *reinterpret_cast<float4*>(&Al[ar * LDA + ah * 16])     = *reinterpret_cast<float4*>(ob);
            *reinterpret_cast<float4*>(&Al[ar * LDA + ah * 16 + 8]) = *reinterpret_cast<float4*>(ob + 8);
            *reinterpret_cast<float4*>(&Bl[ar * LDA + ah * 16])     = pb[0];
            *reinterpret_cast<float4*>(&Bl[ar * LDA + ah * 16 + 8]) = pb[1];
        }
        __syncthreads();
        if (k0 + 32 < H1) {
            pa[0] = *reinterpret_cast<const float4*>(abase + k0 + 32);
            pa[1] = *reinterpret_cast<const float4*>(abase + k0 + 32 + 8);
            pb[0] = *reinterpret_cast<const float4*>(bbase + k0 + 32);
            pb[1] = *reinterpret_cast<const float4*>(bbase + k0 + 32 + 8);
        }
        short8 af[4], bfr[4];
#pragma unroll
        for (int mi = 0; mi < 4; ++mi)
            af[mi] = *reinterpret_cast<const short8*>(&Al[(wm * 64 + mi * 16 + m) * LDA + q * 8]);
#pragma unroll
        for (int ni = 0; ni < 4; ++ni)
            bfr[ni] = *reinterpret_cast<const short8*>(&Bl[(wn * 64 + ni * 16 + m) * LDA + q * 8]);
#pragma unroll
        for (int mi = 0; mi < 4; ++mi)
#pragma unroll
            for (int ni = 0; ni < 4; ++ni)
                acc[mi][ni] = __builtin_amdgcn_mfma_f32_16x16x32_bf16(af[mi], bfr[ni], acc[mi][ni], 0, 0, 0);
    }
    float bias[4];
#pragma unroll
    for (int ni = 0; ni < 4; ++ni) bias[ni] = b2[wn * 64 + ni * 16 + m];
#pragma unroll
    for (int mi = 0; mi < 4; ++mi) {
#pragma unroll
        for (int r = 0; r < 4; ++r) {
            int row = m0 + wm * 64 + mi * 16 + q * 4 + r;
#pragma unroll
            for (int ni = 0; ni < 4; ++ni) {
                int col = wn * 64 + ni * 16 + m;
                z[(size_t)row * H2 + col] = f2bf(fmaxf(acc[mi][ni][r] + bias[ni], 0.f));
            }
        }
    }
}

// ---------------------------------------------------------------- K4: head (cosine + MLP + blend), 64 rows/block
#define LDW3 392

__global__ __launch_bounds__(256)
void head_kernel(const unsigned short* __restrict__ z, const unsigned short* __restrict__ w3t,
                 const float* __restrict__ b3, const float* __restrict__ w4,
                 const float* __restrict__ b4, const float* __restrict__ alpha,
                 const float* __restrict__ beta, float* __restrict__ out) {
    __shared__ __align__(16) unsigned short W3l[64 * LDW3];
    __shared__ float b3s[64], w4s[64];
    __shared__ float smath[64], slearn[64];

    const int t  = threadIdx.x;        // 256
    const int r0 = blockIdx.x * 64;

    // stage W3^T: 64 x 384 bf16 (1536 chunks of 16 elems)
#pragma unroll
    for (int i = 0; i < 6; ++i) {
        int c = t + i * 256;
        int n = c / 24, kc = c - n * 24;
        const float4* src = reinterpret_cast<const float4*>(w3t + n * K3DIM + kc * 16);
        float4 v0 = src[0], v1 = src[1];
        *reinterpret_cast<float4*>(&W3l[n * LDW3 + kc * 16])     = v0;
        *reinterpret_cast<float4*>(&W3l[n * LDW3 + kc * 16 + 8]) = v1;
    }
    if (t < 64) { b3s[t] = b3[t]; w4s[t] = w4[t]; }
    __syncthreads();

    const int wave = t >> 6, lane = t & 63;
    const int m = lane & 15, q = lane >> 4;
    const int wr = wave * 16;
    const int row = r0 + wr + m;

    // load this lane's z chunks straight to registers (each elem read by exactly one lane)
    short8 z1c[4], z2c[4];
#pragma unroll
    for (int c = 0; c < 4; ++c) {
        z1c[c] = *reinterpret_cast<const short8*>(z + (size_t)row * H2 + c * 32 + q * 8);
        z2c[c] = *reinterpret_cast<const short8*>(z + (size_t)(NROWS + row) * H2 + c * 32 + q * 8);
    }

    // combined = [z1*z2 | |z1-z2| | z1+z2] @ W3, with cosine accumulated during seg0
    float d = 0.f, s1 = 0.f, s2 = 0.f;
    f32x4 acc[4] = {};
#pragma unroll
    for (int kb = 0; kb < 12; ++kb) {
        int seg = kb >> 2, c = kb & 3;
        short8 af;
#pragma unroll
        for (int j = 0; j < 8; ++j) {
            float v1 = bf2f((unsigned short)z1c[c][j]);
            float v2 = bf2f((unsigned short)z2c[c][j]);
            float v;
            if (seg == 0) { v = v1 * v2; d += v; s1 += v1 * v1; s2 += v2 * v2; }
            else if (seg == 1) v = fabsf(v1 - v2);
            else v = v1 + v2;
            af[j] = (short)f2bf(v);
        }
#pragma unroll
        for (int ni = 0; ni < 4; ++ni) {
            short8 bfr = *reinterpret_cast<const short8*>(&W3l[(ni * 16 + m) * LDW3 + kb * 32 + q * 8]);
            acc[ni] = __builtin_amdgcn_mfma_f32_16x16x32_bf16(af, bfr, acc[ni], 0, 0, 0);
        }
    }
    // cosine: reduce over q (lane bits 4..5)
    d  += __shfl_xor(d, 16);  d  += __shfl_xor(d, 32);
    s1 += __shfl_xor(s1, 16); s1 += __shfl_xor(s1, 32);
    s2 += __shfl_xor(s2, 16); s2 += __shfl_xor(s2, 32);
    if (q == 0) {
        float inv1 = 1.f / fmaxf(sqrtf(s1), 1e-15f);
        float inv2 = 1.f / fmaxf(sqrtf(s2), 1e-15f);
        smath[wr + m] = fminf(fmaxf(d * inv1 * inv2, 0.f), 1.f);
    }

    // MLP epilogue: relu(acc+b3) . w4, reduce over m (lane bits 0..3)
    float partial[4] = {0.f, 0.f, 0.f, 0.f};
#pragma unroll
    for (int ni = 0; ni < 4; ++ni) {
        int col = ni * 16 + m;
        float bias = b3s[col], w4v = w4s[col];
#pragma unroll
        for (int rg = 0; rg < 4; ++rg) {
            float v = fmaxf(acc[ni][rg] + bias, 0.f);
            partial[rg] += v * w4v;
        }
    }
#pragma unroll
    for (int rg = 0; rg < 4; ++rg) {
        float p = partial[rg];
        p += __shfl_xor(p, 1); p += __shfl_xor(p, 2);
        p += __shfl_xor(p, 4); p += __shfl_xor(p, 8);
        if (m == 0) slearn[wr + q * 4 + rg] = p + b4[0];
    }
    __syncthreads();
    if (t < 64) {
        float sl = slearn[t];
        float sig = 1.f / (1.f + expf(-sl));
        float f = alpha[0] * smath[t] + beta[0] * sig;
        out[r0 + t] = fminf(fmaxf(f, 0.f), 1.f);
    }
}

// ---------------------------------------------------------------- launch
extern "C" void kernel_launch(void* const* d_in, const int* in_sizes, int n_in,
                              void* d_out, int out_size, void* d_ws, size_t ws_size,
                              hipStream_t stream) {
    (void)in_sizes; (void)n_in; (void)out_size; (void)ws_size;
    const float* x1      = (const float*)d_in[0];
    const float* x2      = (const float*)d_in[1];
    const float* W1      = (const float*)d_in[2];
    const float* b1      = (const float*)d_in[3];
    const float* gamma   = (const float*)d_in[4];
    const float* beta_bn = (const float*)d_in[5];
    const float* W2      = (const float*)d_in[6];
    const float* b2      = (const float*)d_in[7];
    const float* W3      = (const float*)d_in[8];
    const float* b3      = (const float*)d_in[9];
    const float* W4      = (const float*)d_in[10];
    const float* b4      = (const float*)d_in[11];
    const float* alpha   = (const float*)d_in[12];
    const float* beta    = (const float*)d_in[13];
    float* out = (float*)d_out;

    char* ws = (char*)d_ws;
    unsigned short* h   = (unsigned short*)(ws);                  // 67108864 B
    unsigned short* w1t = (unsigned short*)(ws + 67108864);       // 262144 B
    unsigned short* w2t = (unsigned short*)(ws + 67371008);       // 65536 B
    unsigned short* w3t = (unsigned short*)(ws + 67436544);       // 49152 B
    float*          ab  = (float*)(ws + 67485696);                // 4096 B
    unsigned short* z   = (unsigned short*)(ws + 67489792);       // 33554432 B
    // P aliases the z region (4 MB): consumed by reduce_bn before gemm2 writes z.
    float*          P   = (float*)(ws + 67489792);

    prep_kernel<<<(DIN * H1 + H1 * H2 + K3DIM * O3 + 255) / 256, 256, 0, stream>>>(W1, W2, W3, w1t, w2t, w3t);
    gemm1_kernel<<<dim3(2, 1024), 256, 0, stream>>>(x1, x2, w1t, b1, h, P);
    reduce_bn_kernel<<<2, 512, 0, stream>>>(P, gamma, beta_bn, ab);
    gemm2_kernel<<<1024, 256, 0, stream>>>(h, w2t, b2, ab, z);
    head_kernel<<<1024, 256, 0, stream>>>(z, w3t, b3, W4, b4, alpha, beta, out);
}